// Round 10
// baseline (147.317 us; speedup 1.0000x reference)
//
#include <hip/hip_runtime.h>

#define HM_B 32
#define HM_C 98
#define HM_H 128
#define HM_W 128
#define HWSZ (HM_H * HM_W)          // 16384
#define FDIM 256
#define DDIM 128
#define NODE_F (2 + 1 + FDIM)       // 259
#define NODE_P 260                  // padded row stride in node_ws
#define BC (HM_B * HM_C)            // 3136
#define HM_ELEMS ((size_t)BC * HWSZ)
#define LCHUNK 8                    // landmarks per embed block (392 blocks)
#define ICHUNK 7                    // rows per gcn block (448 blocks)
#define NTHR 256

typedef float f32x4 __attribute__((ext_vector_type(4)));

// Kernel 1: per (b,c) row — copy hm->out, argmax (first occurrence), gather.
// Depth-4 double-buffered pipeline (R9). SINGLE CHANGE vs R9: PLAIN stores
// instead of nontemporal — hypothesis: NT stores bypass L2 write-back
// aggregation (write-through per 128B line), capping the write stream; the
// harness fills reach 6.6+ TB/s with plain stores.
__global__ __launch_bounds__(NTHR) void k1_copy_argmax_gather(
    const float* __restrict__ hm, const float* __restrict__ feat,
    float* __restrict__ out_hm, float* __restrict__ node_ws) {
    const int row = blockIdx.x;
    const int tid = threadIdx.x;
    const f32x4* __restrict__ src = (const f32x4*)(hm + (size_t)row * HWSZ);
    f32x4* __restrict__ dst = (f32x4*)(out_hm + (size_t)row * HWSZ);

    float bv = -INFINITY;
    int bi = 0;
    f32x4 cur0 = src[0 * NTHR + tid];
    f32x4 cur1 = src[1 * NTHR + tid];
    f32x4 cur2 = src[2 * NTHR + tid];
    f32x4 cur3 = src[3 * NTHR + tid];
    #pragma unroll
    for (int g = 0; g < 4; ++g) {
        f32x4 nxt0, nxt1, nxt2, nxt3;
        if (g < 3) {                      // compile-time after unroll
            nxt0 = src[((g + 1) * 4 + 0) * NTHR + tid];
            nxt1 = src[((g + 1) * 4 + 1) * NTHR + tid];
            nxt2 = src[((g + 1) * 4 + 2) * NTHR + tid];
            nxt3 = src[((g + 1) * 4 + 3) * NTHR + tid];
        }
        #pragma unroll
        for (int u = 0; u < 4; ++u) {
            const f32x4 v = (u == 0) ? cur0 : (u == 1) ? cur1 : (u == 2) ? cur2 : cur3;
            const int t = g * 4 + u;
            const int p = t * NTHR + tid;
            dst[p] = v;                   // plain store: L2 write-back path
            const float m4 = fmaxf(fmaxf(v[0], v[1]), fmaxf(v[2], v[3]));
            if (m4 > bv) {  // in-order scan keeps first occurrence per thread
                const int base = p * 4;
                if (v[0] > bv) { bv = v[0]; bi = base; }
                if (v[1] > bv) { bv = v[1]; bi = base + 1; }
                if (v[2] > bv) { bv = v[2]; bi = base + 2; }
                if (v[3] > bv) { bv = v[3]; bi = base + 3; }
            }
        }
        cur0 = nxt0; cur1 = nxt1; cur2 = nxt2; cur3 = nxt3;
    }

    __shared__ float sv[NTHR];
    __shared__ int si[NTHR];
    sv[tid] = bv; si[tid] = bi;
    __syncthreads();
    for (int s = NTHR / 2; s > 0; s >>= 1) {
        if (tid < s) {
            const float ov = sv[tid + s];
            const int oi = si[tid + s];
            if (ov > sv[tid] || (ov == sv[tid] && oi < si[tid])) {
                sv[tid] = ov; si[tid] = oi;
            }
        }
        __syncthreads();
    }

    const int loc = si[0];
    const float conf = sv[0];
    const int b = row / HM_C;
    // one scattered 64B-line NT load per thread (use-once: keep out of L3)
    const float vis = __builtin_nontemporal_load(
        feat + ((size_t)(b * FDIM + tid)) * HWSZ + loc);
    float* nrow = node_ws + (size_t)row * NODE_P;
    nrow[3 + tid] = vis;
    if (tid == 0) {
        nrow[0] = (float)(loc % HM_W) * (1.0f / (float)HM_H);  // ref: [xs,ys]/[H,W]
        nrow[1] = (float)(loc / HM_W) * (1.0f / (float)HM_W);
        nrow[2] = conf;
    }
}

// Kernel 2: h0 = relu(node @ W_embed + b_embed), 8 landmarks/block.
// Writes h0 IN-PLACE over node_ws[row][0:128] (row fully staged to LDS first).
__global__ __launch_bounds__(NTHR) void k2_embed(
    float* __restrict__ node_ws, const float* __restrict__ W_embed,
    const float* __restrict__ b_embed) {
    const int bc0 = blockIdx.x * LCHUNK;
    const int tid = threadIdx.x;
    __shared__ float node_s[LCHUNK][NODE_P];  // 8*260*4 = 8320 B

    #pragma unroll
    for (int l = 0; l < LCHUNK; ++l)
        for (int k = tid; k < NODE_F; k += NTHR)
            node_s[l][k] = node_ws[(size_t)(bc0 + l) * NODE_P + k];
    __syncthreads();

    const int d = tid & (DDIM - 1);
    const int lbase = (tid >> 7) * 4;
    const float bias = b_embed[d];
    float a0 = bias, a1 = bias, a2 = bias, a3 = bias;
    for (int f = 0; f < NODE_F; ++f) {
        const float w = W_embed[f * DDIM + d];
        a0 = fmaf(node_s[lbase + 0][f], w, a0);
        a1 = fmaf(node_s[lbase + 1][f], w, a1);
        a2 = fmaf(node_s[lbase + 2][f], w, a2);
        a3 = fmaf(node_s[lbase + 3][f], w, a3);
    }
    node_ws[(size_t)(bc0 + lbase + 0) * NODE_P + d] = fmaxf(a0, 0.f);
    node_ws[(size_t)(bc0 + lbase + 1) * NODE_P + d] = fmaxf(a1, 0.f);
    node_ws[(size_t)(bc0 + lbase + 2) * NODE_P + d] = fmaxf(a2, 0.f);
    node_ws[(size_t)(bc0 + lbase + 3) * NODE_P + d] = fmaxf(a3, 0.f);
}

// Kernel 3: h1 = relu((A @ h0) @ W_gcn); out2 = h1 @ W_out + b_out.
// h0 lives in node_ws rows (stride NODE_P), L2/L3-resident.
__global__ __launch_bounds__(DDIM) void k3_gcn(
    const float* __restrict__ A, const float* __restrict__ node_ws,
    const float* __restrict__ W_gcn, const float* __restrict__ W_out,
    const float* __restrict__ b_out, float* __restrict__ out2) {
    const int b = blockIdx.x / (HM_C / ICHUNK);
    const int i0 = (blockIdx.x % (HM_C / ICHUNK)) * ICHUNK;
    const int tid = threadIdx.x;           // = d

    __shared__ float arow[ICHUNK * HM_C];  // 2744 B
    __shared__ float tmp_s[ICHUNK * DDIM]; // 3584 B
    __shared__ float h1_s[ICHUNK * DDIM];  // 3584 B

    for (int k = tid; k < ICHUNK * HM_C; k += DDIM)
        arow[k] = A[(i0 + k / HM_C) * HM_C + (k % HM_C)];
    __syncthreads();

    {
        float acc[ICHUNK];
        #pragma unroll
        for (int i = 0; i < ICHUNK; ++i) acc[i] = 0.f;
        for (int j = 0; j < HM_C; ++j) {
            const float v = node_ws[((size_t)b * HM_C + j) * NODE_P + tid];
            #pragma unroll
            for (int i = 0; i < ICHUNK; ++i)
                acc[i] = fmaf(arow[i * HM_C + j], v, acc[i]);
        }
        #pragma unroll
        for (int i = 0; i < ICHUNK; ++i) tmp_s[i * DDIM + tid] = acc[i];
    }
    __syncthreads();

    {
        float acc[ICHUNK];
        #pragma unroll
        for (int i = 0; i < ICHUNK; ++i) acc[i] = 0.f;
        for (int k = 0; k < DDIM; ++k) {
            const float w = W_gcn[k * DDIM + tid];
            #pragma unroll
            for (int i = 0; i < ICHUNK; ++i)
                acc[i] = fmaf(tmp_s[i * DDIM + k], w, acc[i]);
        }
        #pragma unroll
        for (int i = 0; i < ICHUNK; ++i) h1_s[i * DDIM + tid] = fmaxf(acc[i], 0.f);
    }
    __syncthreads();

    if (tid < ICHUNK * 2) {
        const int i = tid >> 1;
        const int o = tid & 1;
        float acc = b_out[o];
        for (int dd = 0; dd < DDIM; ++dd)
            acc = fmaf(h1_s[i * DDIM + dd], W_out[dd * 2 + o], acc);
        out2[((size_t)b * HM_C + i0 + i) * 2 + o] = acc;
    }
}

extern "C" void kernel_launch(void* const* d_in, const int* in_sizes, int n_in,
                              void* d_out, int out_size, void* d_ws, size_t ws_size,
                              hipStream_t stream) {
    const float* hm      = (const float*)d_in[0];
    const float* feat    = (const float*)d_in[1];
    const float* W_embed = (const float*)d_in[2];
    const float* b_embed = (const float*)d_in[3];
    const float* A       = (const float*)d_in[4];
    const float* W_gcn   = (const float*)d_in[5];
    const float* W_out   = (const float*)d_in[6];
    const float* b_out   = (const float*)d_in[7];

    float* out_hm = (float*)d_out;                 // [B,C,H,W] passthrough
    float* out2   = (float*)d_out + HM_ELEMS;      // [B,C,2]

    float* node_ws = (float*)d_ws;                 // BC x NODE_P = 3.26 MB

    k1_copy_argmax_gather<<<BC, NTHR, 0, stream>>>(hm, feat, out_hm, node_ws);
    k2_embed<<<BC / LCHUNK, NTHR, 0, stream>>>(node_ws, W_embed, b_embed);
    k3_gcn<<<HM_B * (HM_C / ICHUNK), DDIM, 0, stream>>>(A, node_ws, W_gcn,
                                                        W_out, b_out, out2);
}

// Round 11
// 120.417 us; speedup vs baseline: 1.2234x; 1.2234x over previous
//
#include <hip/hip_runtime.h>

#define HM_B 32
#define HM_C 98
#define HM_H 128
#define HM_W 128
#define HWSZ (HM_H * HM_W)          // 16384
#define FDIM 256
#define DDIM 128
#define NODE_F (2 + 1 + FDIM)       // 259
#define NODE_P 260                  // padded row stride in node_ws
#define BC (HM_B * HM_C)            // 3136
#define HM_ELEMS ((size_t)BC * HWSZ)
#define LCHUNK 8                    // landmarks per embed block (392 blocks)
#define ICHUNK 7                    // rows per gcn block (448 blocks)
#define NTHR 256

typedef float f32x4 __attribute__((ext_vector_type(4)));

// Kernel 1: per (b,c) row — copy hm->out, argmax (first occurrence), gather.
// Structure vs R9 (single variable): the WHOLE row is loaded into registers
// first (16 back-to-back wave-loads), argmax-consumed (vmcnt waits see only
// loads — no older NT stores to drain), reduced, and only THEN are the 16 NT
// stores issued. This decouples load consumption from ~900-cycle NT-store
// retirement, which share the vmcnt counter.
__global__ __launch_bounds__(NTHR) void k1_copy_argmax_gather(
    const float* __restrict__ hm, const float* __restrict__ feat,
    float* __restrict__ out_hm, float* __restrict__ node_ws) {
    const int row = blockIdx.x;
    const int tid = threadIdx.x;
    const f32x4* __restrict__ src = (const f32x4*)(hm + (size_t)row * HWSZ);
    f32x4* __restrict__ dst = (f32x4*)(out_hm + (size_t)row * HWSZ);

    // issue all 16 loads back-to-back (temporal: L3-allocate hm)
    f32x4 v[16];
    #pragma unroll
    for (int t = 0; t < 16; ++t)
        v[t] = src[t * NTHR + tid];

    // consume in order; waits are load-only, released incrementally
    float bv = -INFINITY;
    int bi = 0;
    #pragma unroll
    for (int t = 0; t < 16; ++t) {
        const f32x4 x = v[t];
        const int base = (t * NTHR + tid) * 4;
        const float m4 = fmaxf(fmaxf(x[0], x[1]), fmaxf(x[2], x[3]));
        if (m4 > bv) {  // in-order scan keeps first occurrence per thread
            if (x[0] > bv) { bv = x[0]; bi = base; }
            if (x[1] > bv) { bv = x[1]; bi = base + 1; }
            if (x[2] > bv) { bv = x[2]; bi = base + 2; }
            if (x[3] > bv) { bv = x[3]; bi = base + 3; }
        }
    }

    // block reduce: barriers here drain nothing (loads done, no stores yet)
    __shared__ float sv[NTHR];
    __shared__ int si[NTHR];
    sv[tid] = bv; si[tid] = bi;
    __syncthreads();
    for (int s = NTHR / 2; s > 0; s >>= 1) {
        if (tid < s) {
            const float ov = sv[tid + s];
            const int oi = si[tid + s];
            if (ov > sv[tid] || (ov == sv[tid] && oi < si[tid])) {
                sv[tid] = ov; si[tid] = oi;
            }
        }
        __syncthreads();
    }
    const int loc = si[0];
    const float conf = sv[0];

    // now emit the copy: 16 NT stores (bypass L2/L3 write-allocate)
    #pragma unroll
    for (int t = 0; t < 16; ++t)
        __builtin_nontemporal_store(v[t], dst + t * NTHR + tid);

    // gather: one scattered 64B-line NT load per thread (use-once)
    const int b = row / HM_C;
    const float vis = __builtin_nontemporal_load(
        feat + ((size_t)(b * FDIM + tid)) * HWSZ + loc);
    float* nrow = node_ws + (size_t)row * NODE_P;
    nrow[3 + tid] = vis;
    if (tid == 0) {
        nrow[0] = (float)(loc % HM_W) * (1.0f / (float)HM_H);  // ref: [xs,ys]/[H,W]
        nrow[1] = (float)(loc / HM_W) * (1.0f / (float)HM_W);
        nrow[2] = conf;
    }
}

// Kernel 2: h0 = relu(node @ W_embed + b_embed), 8 landmarks/block.
// Writes h0 IN-PLACE over node_ws[row][0:128] (row fully staged to LDS first).
__global__ __launch_bounds__(NTHR) void k2_embed(
    float* __restrict__ node_ws, const float* __restrict__ W_embed,
    const float* __restrict__ b_embed) {
    const int bc0 = blockIdx.x * LCHUNK;
    const int tid = threadIdx.x;
    __shared__ float node_s[LCHUNK][NODE_P];  // 8*260*4 = 8320 B

    #pragma unroll
    for (int l = 0; l < LCHUNK; ++l)
        for (int k = tid; k < NODE_F; k += NTHR)
            node_s[l][k] = node_ws[(size_t)(bc0 + l) * NODE_P + k];
    __syncthreads();

    const int d = tid & (DDIM - 1);
    const int lbase = (tid >> 7) * 4;
    const float bias = b_embed[d];
    float a0 = bias, a1 = bias, a2 = bias, a3 = bias;
    for (int f = 0; f < NODE_F; ++f) {
        const float w = W_embed[f * DDIM + d];
        a0 = fmaf(node_s[lbase + 0][f], w, a0);
        a1 = fmaf(node_s[lbase + 1][f], w, a1);
        a2 = fmaf(node_s[lbase + 2][f], w, a2);
        a3 = fmaf(node_s[lbase + 3][f], w, a3);
    }
    node_ws[(size_t)(bc0 + lbase + 0) * NODE_P + d] = fmaxf(a0, 0.f);
    node_ws[(size_t)(bc0 + lbase + 1) * NODE_P + d] = fmaxf(a1, 0.f);
    node_ws[(size_t)(bc0 + lbase + 2) * NODE_P + d] = fmaxf(a2, 0.f);
    node_ws[(size_t)(bc0 + lbase + 3) * NODE_P + d] = fmaxf(a3, 0.f);
}

// Kernel 3: h1 = relu((A @ h0) @ W_gcn); out2 = h1 @ W_out + b_out.
// h0 lives in node_ws rows (stride NODE_P), L2/L3-resident.
__global__ __launch_bounds__(DDIM) void k3_gcn(
    const float* __restrict__ A, const float* __restrict__ node_ws,
    const float* __restrict__ W_gcn, const float* __restrict__ W_out,
    const float* __restrict__ b_out, float* __restrict__ out2) {
    const int b = blockIdx.x / (HM_C / ICHUNK);
    const int i0 = (blockIdx.x % (HM_C / ICHUNK)) * ICHUNK;
    const int tid = threadIdx.x;           // = d

    __shared__ float arow[ICHUNK * HM_C];  // 2744 B
    __shared__ float tmp_s[ICHUNK * DDIM]; // 3584 B
    __shared__ float h1_s[ICHUNK * DDIM];  // 3584 B

    for (int k = tid; k < ICHUNK * HM_C; k += DDIM)
        arow[k] = A[(i0 + k / HM_C) * HM_C + (k % HM_C)];
    __syncthreads();

    {
        float acc[ICHUNK];
        #pragma unroll
        for (int i = 0; i < ICHUNK; ++i) acc[i] = 0.f;
        for (int j = 0; j < HM_C; ++j) {
            const float v = node_ws[((size_t)b * HM_C + j) * NODE_P + tid];
            #pragma unroll
            for (int i = 0; i < ICHUNK; ++i)
                acc[i] = fmaf(arow[i * HM_C + j], v, acc[i]);
        }
        #pragma unroll
        for (int i = 0; i < ICHUNK; ++i) tmp_s[i * DDIM + tid] = acc[i];
    }
    __syncthreads();

    {
        float acc[ICHUNK];
        #pragma unroll
        for (int i = 0; i < ICHUNK; ++i) acc[i] = 0.f;
        for (int k = 0; k < DDIM; ++k) {
            const float w = W_gcn[k * DDIM + tid];
            #pragma unroll
            for (int i = 0; i < ICHUNK; ++i)
                acc[i] = fmaf(tmp_s[i * DDIM + k], w, acc[i]);
        }
        #pragma unroll
        for (int i = 0; i < ICHUNK; ++i) h1_s[i * DDIM + tid] = fmaxf(acc[i], 0.f);
    }
    __syncthreads();

    if (tid < ICHUNK * 2) {
        const int i = tid >> 1;
        const int o = tid & 1;
        float acc = b_out[o];
        for (int dd = 0; dd < DDIM; ++dd)
            acc = fmaf(h1_s[i * DDIM + dd], W_out[dd * 2 + o], acc);
        out2[((size_t)b * HM_C + i0 + i) * 2 + o] = acc;
    }
}

extern "C" void kernel_launch(void* const* d_in, const int* in_sizes, int n_in,
                              void* d_out, int out_size, void* d_ws, size_t ws_size,
                              hipStream_t stream) {
    const float* hm      = (const float*)d_in[0];
    const float* feat    = (const float*)d_in[1];
    const float* W_embed = (const float*)d_in[2];
    const float* b_embed = (const float*)d_in[3];
    const float* A       = (const float*)d_in[4];
    const float* W_gcn   = (const float*)d_in[5];
    const float* W_out   = (const float*)d_in[6];
    const float* b_out   = (const float*)d_in[7];

    float* out_hm = (float*)d_out;                 // [B,C,H,W] passthrough
    float* out2   = (float*)d_out + HM_ELEMS;      // [B,C,2]

    float* node_ws = (float*)d_ws;                 // BC x NODE_P = 3.26 MB

    k1_copy_argmax_gather<<<BC, NTHR, 0, stream>>>(hm, feat, out_hm, node_ws);
    k2_embed<<<BC / LCHUNK, NTHR, 0, stream>>>(node_ws, W_embed, b_embed);
    k3_gcn<<<HM_B * (HM_C / ICHUNK), DDIM, 0, stream>>>(A, node_ws, W_gcn,
                                                        W_out, b_out, out2);
}

// Round 12
// 120.071 us; speedup vs baseline: 1.2269x; 1.0029x over previous
//
#include <hip/hip_runtime.h>

#define HM_B 32
#define HM_C 98
#define HM_H 128
#define HM_W 128
#define HWSZ (HM_H * HM_W)          // 16384
#define FDIM 256
#define DDIM 128
#define NODE_F (2 + 1 + FDIM)       // 259
#define NODE_P 260                  // padded row stride in node_ws
#define BC (HM_B * HM_C)            // 3136
#define HM_ELEMS ((size_t)BC * HWSZ)
#define LCHUNK 8                    // landmarks per embed block (392 blocks)
#define ICHUNK 7                    // rows per gcn block (448 blocks)
#define NTHR 256

typedef float f32x4 __attribute__((ext_vector_type(4)));

// Kernel 1: per (b,c) row — copy hm->out, argmax (first occurrence), gather.
// SINGLE VARIABLE vs R9/R11: block reduction uses a per-wave __shfl_xor
// butterfly (in-register) + ONE __syncthreads (4 LDS slots), instead of the
// 8-round LDS tree. Stores are issued after the barrier (R11-proven neutral),
// so the lone barrier drains nothing. Temporal loads + NT stores (proven).
__global__ __launch_bounds__(NTHR) void k1_copy_argmax_gather(
    const float* __restrict__ hm, const float* __restrict__ feat,
    float* __restrict__ out_hm, float* __restrict__ node_ws) {
    const int row = blockIdx.x;
    const int tid = threadIdx.x;
    const f32x4* __restrict__ src = (const f32x4*)(hm + (size_t)row * HWSZ);
    f32x4* __restrict__ dst = (f32x4*)(out_hm + (size_t)row * HWSZ);

    // issue all 16 loads back-to-back; consume in order (incremental vmcnt)
    f32x4 v[16];
    #pragma unroll
    for (int t = 0; t < 16; ++t)
        v[t] = src[t * NTHR + tid];

    float bv = -INFINITY;
    int bi = 0;
    #pragma unroll
    for (int t = 0; t < 16; ++t) {
        const f32x4 x = v[t];
        const int base = (t * NTHR + tid) * 4;
        const float m4 = fmaxf(fmaxf(x[0], x[1]), fmaxf(x[2], x[3]));
        if (m4 > bv) {  // in-order scan keeps first occurrence per thread
            if (x[0] > bv) { bv = x[0]; bi = base; }
            if (x[1] > bv) { bv = x[1]; bi = base + 1; }
            if (x[2] > bv) { bv = x[2]; bi = base + 2; }
            if (x[3] > bv) { bv = x[3]; bi = base + 3; }
        }
    }

    // wave butterfly: (max value, min index on tie) is associative
    #pragma unroll
    for (int s = 1; s < 64; s <<= 1) {
        const float ov = __shfl_xor(bv, s, 64);
        const int oi = __shfl_xor(bi, s, 64);
        if (ov > bv || (ov == bv && oi < bi)) { bv = ov; bi = oi; }
    }

    // single barrier: 4 per-wave partials -> all threads combine redundantly
    __shared__ float wv[NTHR / 64];
    __shared__ int wi[NTHR / 64];
    if ((tid & 63) == 0) { wv[tid >> 6] = bv; wi[tid >> 6] = bi; }
    __syncthreads();        // drains nothing: no stores issued yet, loads done
    float fv = wv[0]; int fi = wi[0];
    #pragma unroll
    for (int w = 1; w < NTHR / 64; ++w) {
        const float ov = wv[w]; const int oi = wi[w];
        if (ov > fv || (ov == fv && oi < fi)) { fv = ov; fi = oi; }
    }
    const int loc = fi;
    const float conf = fv;

    // emit the copy: 16 NT stores (bypass L2/L3 write-allocate)
    #pragma unroll
    for (int t = 0; t < 16; ++t)
        __builtin_nontemporal_store(v[t], dst + t * NTHR + tid);

    // gather: one scattered 64B-line NT load per thread (use-once)
    const int b = row / HM_C;
    const float vis = __builtin_nontemporal_load(
        feat + ((size_t)(b * FDIM + tid)) * HWSZ + loc);
    float* nrow = node_ws + (size_t)row * NODE_P;
    nrow[3 + tid] = vis;
    if (tid == 0) {
        nrow[0] = (float)(loc % HM_W) * (1.0f / (float)HM_H);  // ref: [xs,ys]/[H,W]
        nrow[1] = (float)(loc / HM_W) * (1.0f / (float)HM_W);
        nrow[2] = conf;
    }
}

// Kernel 2: h0 = relu(node @ W_embed + b_embed), 8 landmarks/block.
// Writes h0 IN-PLACE over node_ws[row][0:128] (row fully staged to LDS first).
__global__ __launch_bounds__(NTHR) void k2_embed(
    float* __restrict__ node_ws, const float* __restrict__ W_embed,
    const float* __restrict__ b_embed) {
    const int bc0 = blockIdx.x * LCHUNK;
    const int tid = threadIdx.x;
    __shared__ float node_s[LCHUNK][NODE_P];  // 8*260*4 = 8320 B

    #pragma unroll
    for (int l = 0; l < LCHUNK; ++l)
        for (int k = tid; k < NODE_F; k += NTHR)
            node_s[l][k] = node_ws[(size_t)(bc0 + l) * NODE_P + k];
    __syncthreads();

    const int d = tid & (DDIM - 1);
    const int lbase = (tid >> 7) * 4;
    const float bias = b_embed[d];
    float a0 = bias, a1 = bias, a2 = bias, a3 = bias;
    for (int f = 0; f < NODE_F; ++f) {
        const float w = W_embed[f * DDIM + d];
        a0 = fmaf(node_s[lbase + 0][f], w, a0);
        a1 = fmaf(node_s[lbase + 1][f], w, a1);
        a2 = fmaf(node_s[lbase + 2][f], w, a2);
        a3 = fmaf(node_s[lbase + 3][f], w, a3);
    }
    node_ws[(size_t)(bc0 + lbase + 0) * NODE_P + d] = fmaxf(a0, 0.f);
    node_ws[(size_t)(bc0 + lbase + 1) * NODE_P + d] = fmaxf(a1, 0.f);
    node_ws[(size_t)(bc0 + lbase + 2) * NODE_P + d] = fmaxf(a2, 0.f);
    node_ws[(size_t)(bc0 + lbase + 3) * NODE_P + d] = fmaxf(a3, 0.f);
}

// Kernel 3: h1 = relu((A @ h0) @ W_gcn); out2 = h1 @ W_out + b_out.
// h0 lives in node_ws rows (stride NODE_P), L2/L3-resident.
__global__ __launch_bounds__(DDIM) void k3_gcn(
    const float* __restrict__ A, const float* __restrict__ node_ws,
    const float* __restrict__ W_gcn, const float* __restrict__ W_out,
    const float* __restrict__ b_out, float* __restrict__ out2) {
    const int b = blockIdx.x / (HM_C / ICHUNK);
    const int i0 = (blockIdx.x % (HM_C / ICHUNK)) * ICHUNK;
    const int tid = threadIdx.x;           // = d

    __shared__ float arow[ICHUNK * HM_C];  // 2744 B
    __shared__ float tmp_s[ICHUNK * DDIM]; // 3584 B
    __shared__ float h1_s[ICHUNK * DDIM];  // 3584 B

    for (int k = tid; k < ICHUNK * HM_C; k += DDIM)
        arow[k] = A[(i0 + k / HM_C) * HM_C + (k % HM_C)];
    __syncthreads();

    {
        float acc[ICHUNK];
        #pragma unroll
        for (int i = 0; i < ICHUNK; ++i) acc[i] = 0.f;
        for (int j = 0; j < HM_C; ++j) {
            const float v = node_ws[((size_t)b * HM_C + j) * NODE_P + tid];
            #pragma unroll
            for (int i = 0; i < ICHUNK; ++i)
                acc[i] = fmaf(arow[i * HM_C + j], v, acc[i]);
        }
        #pragma unroll
        for (int i = 0; i < ICHUNK; ++i) tmp_s[i * DDIM + tid] = acc[i];
    }
    __syncthreads();

    {
        float acc[ICHUNK];
        #pragma unroll
        for (int i = 0; i < ICHUNK; ++i) acc[i] = 0.f;
        for (int k = 0; k < DDIM; ++k) {
            const float w = W_gcn[k * DDIM + tid];
            #pragma unroll
            for (int i = 0; i < ICHUNK; ++i)
                acc[i] = fmaf(tmp_s[i * DDIM + k], w, acc[i]);
        }
        #pragma unroll
        for (int i = 0; i < ICHUNK; ++i) h1_s[i * DDIM + tid] = fmaxf(acc[i], 0.f);
    }
    __syncthreads();

    if (tid < ICHUNK * 2) {
        const int i = tid >> 1;
        const int o = tid & 1;
        float acc = b_out[o];
        for (int dd = 0; dd < DDIM; ++dd)
            acc = fmaf(h1_s[i * DDIM + dd], W_out[dd * 2 + o], acc);
        out2[((size_t)b * HM_C + i0 + i) * 2 + o] = acc;
    }
}

extern "C" void kernel_launch(void* const* d_in, const int* in_sizes, int n_in,
                              void* d_out, int out_size, void* d_ws, size_t ws_size,
                              hipStream_t stream) {
    const float* hm      = (const float*)d_in[0];
    const float* feat    = (const float*)d_in[1];
    const float* W_embed = (const float*)d_in[2];
    const float* b_embed = (const float*)d_in[3];
    const float* A       = (const float*)d_in[4];
    const float* W_gcn   = (const float*)d_in[5];
    const float* W_out   = (const float*)d_in[6];
    const float* b_out   = (const float*)d_in[7];

    float* out_hm = (float*)d_out;                 // [B,C,H,W] passthrough
    float* out2   = (float*)d_out + HM_ELEMS;      // [B,C,2]

    float* node_ws = (float*)d_ws;                 // BC x NODE_P = 3.26 MB

    k1_copy_argmax_gather<<<BC, NTHR, 0, stream>>>(hm, feat, out_hm, node_ws);
    k2_embed<<<BC / LCHUNK, NTHR, 0, stream>>>(node_ws, W_embed, b_embed);
    k3_gcn<<<HM_B * (HM_C / ICHUNK), DDIM, 0, stream>>>(A, node_ws, W_gcn,
                                                        W_out, b_out, out2);
}

// Round 14
// 109.584 us; speedup vs baseline: 1.3443x; 1.0957x over previous
//
#include <hip/hip_runtime.h>

#define HM_B 32
#define HM_C 98
#define HM_H 128
#define HM_W 128
#define HWSZ (HM_H * HM_W)          // 16384
#define FDIM 256
#define DDIM 128
#define NODE_F (2 + 1 + FDIM)       // 259
#define NODE_P 260                  // padded LDS row stride
#define BC (HM_B * HM_C)            // 3136
#define HM_ELEMS ((size_t)BC * HWSZ)
#define LCHUNK 8                    // landmarks per embed block (392 blocks)
#define ICHUNK 7                    // rows per gcn block (448 blocks)
#define NTHR 256
#define NWAVE (NTHR / 64)           // 4 waves per block

typedef float f32x4 __attribute__((ext_vector_type(4)));

// Kernel 1: PURE stream + in-register argmax. Per row: R9's proven depth-4
// pipelined copy (temporal loads, NT stores), wave-level shfl butterfly,
// one 8B partial per wave (plain store -> L2, k2 reads it immediately).
// NO LDS, NO barrier, NO gather tail — block retires as soon as stores drain.
__global__ __launch_bounds__(NTHR) void k1_copy_argmax(
    const float* __restrict__ hm, float* __restrict__ out_hm,
    float* __restrict__ pconf, int* __restrict__ pidx) {
    const int row = blockIdx.x;
    const int tid = threadIdx.x;
    const f32x4* __restrict__ src = (const f32x4*)(hm + (size_t)row * HWSZ);
    f32x4* __restrict__ dst = (f32x4*)(out_hm + (size_t)row * HWSZ);

    float bv = -INFINITY;
    int bi = 0;
    f32x4 cur0 = src[0 * NTHR + tid];
    f32x4 cur1 = src[1 * NTHR + tid];
    f32x4 cur2 = src[2 * NTHR + tid];
    f32x4 cur3 = src[3 * NTHR + tid];
    #pragma unroll
    for (int g = 0; g < 4; ++g) {
        f32x4 nxt0, nxt1, nxt2, nxt3;
        if (g < 3) {                      // compile-time after unroll
            nxt0 = src[((g + 1) * 4 + 0) * NTHR + tid];
            nxt1 = src[((g + 1) * 4 + 1) * NTHR + tid];
            nxt2 = src[((g + 1) * 4 + 2) * NTHR + tid];
            nxt3 = src[((g + 1) * 4 + 3) * NTHR + tid];
        }
        #pragma unroll
        for (int u = 0; u < 4; ++u) {
            const f32x4 v = (u == 0) ? cur0 : (u == 1) ? cur1 : (u == 2) ? cur2 : cur3;
            const int p = (g * 4 + u) * NTHR + tid;
            __builtin_nontemporal_store(v, dst + p);
            const float m4 = fmaxf(fmaxf(v[0], v[1]), fmaxf(v[2], v[3]));
            if (m4 > bv) {  // in-order scan keeps first occurrence per thread
                const int base = p * 4;
                if (v[0] > bv) { bv = v[0]; bi = base; }
                if (v[1] > bv) { bv = v[1]; bi = base + 1; }
                if (v[2] > bv) { bv = v[2]; bi = base + 2; }
                if (v[3] > bv) { bv = v[3]; bi = base + 3; }
            }
        }
        cur0 = nxt0; cur1 = nxt1; cur2 = nxt2; cur3 = nxt3;
    }

    // wave butterfly: (max value, min index on tie) is associative
    #pragma unroll
    for (int s = 1; s < 64; s <<= 1) {
        const float ov = __shfl_xor(bv, s, 64);
        const int oi = __shfl_xor(bi, s, 64);
        if (ov > bv || (ov == bv && oi < bi)) { bv = ov; bi = oi; }
    }
    if ((tid & 63) == 0) {               // one 8B partial per wave, L2-resident
        pconf[row * NWAVE + (tid >> 6)] = bv;
        pidx[row * NWAVE + (tid >> 6)] = bi;
    }
}

// Kernel 2: combine wave partials, 8-way-MLP feature gather, embed.
// h0[bc,d] = relu(node . W_embed[:,d] + b_embed[d])
__global__ __launch_bounds__(NTHR) void k2_embed(
    const float* __restrict__ feat, const float* __restrict__ pconf,
    const int* __restrict__ pidx, const float* __restrict__ W_embed,
    const float* __restrict__ b_embed, float* __restrict__ h0_ws) {
    const int bc0 = blockIdx.x * LCHUNK;
    const int tid = threadIdx.x;
    __shared__ float node_s[LCHUNK][NODE_P];   // 8*260*4 = 8320 B
    __shared__ int locs[LCHUNK];

    if (tid < LCHUNK) {
        const int row = bc0 + tid;
        float fv = pconf[row * NWAVE];
        int fi = pidx[row * NWAVE];
        #pragma unroll
        for (int w = 1; w < NWAVE; ++w) {
            const float ov = pconf[row * NWAVE + w];
            const int oi = pidx[row * NWAVE + w];
            if (ov > fv || (ov == fv && oi < fi)) { fv = ov; fi = oi; }
        }
        locs[tid] = fi;
        node_s[tid][0] = (float)(fi % HM_W) * (1.0f / (float)HM_H);  // ref: [xs,ys]/[H,W]
        node_s[tid][1] = (float)(fi / HM_W) * (1.0f / (float)HM_W);
        node_s[tid][2] = fv;
    }
    __syncthreads();

    // gather: 8 independent scattered 64B-line NT loads per thread (8-way MLP)
    float g[LCHUNK];
    #pragma unroll
    for (int l = 0; l < LCHUNK; ++l) {
        const int bb = (bc0 + l) / HM_C;
        g[l] = __builtin_nontemporal_load(
            feat + ((size_t)(bb * FDIM + tid)) * HWSZ + locs[l]);
    }
    #pragma unroll
    for (int l = 0; l < LCHUNK; ++l)
        node_s[l][3 + tid] = g[l];
    __syncthreads();

    const int d = tid & (DDIM - 1);
    const int lbase = (tid >> 7) * 4;
    const float bias = b_embed[d];
    float a0 = bias, a1 = bias, a2 = bias, a3 = bias;
    for (int f = 0; f < NODE_F; ++f) {
        const float w = W_embed[f * DDIM + d];
        a0 = fmaf(node_s[lbase + 0][f], w, a0);
        a1 = fmaf(node_s[lbase + 1][f], w, a1);
        a2 = fmaf(node_s[lbase + 2][f], w, a2);
        a3 = fmaf(node_s[lbase + 3][f], w, a3);
    }
    h0_ws[(size_t)(bc0 + lbase + 0) * DDIM + d] = fmaxf(a0, 0.f);
    h0_ws[(size_t)(bc0 + lbase + 1) * DDIM + d] = fmaxf(a1, 0.f);
    h0_ws[(size_t)(bc0 + lbase + 2) * DDIM + d] = fmaxf(a2, 0.f);
    h0_ws[(size_t)(bc0 + lbase + 3) * DDIM + d] = fmaxf(a3, 0.f);
}

// Kernel 3: h1 = relu((A @ h0) @ W_gcn); out2 = h1 @ W_out + b_out.
__global__ __launch_bounds__(DDIM) void k3_gcn(
    const float* __restrict__ A, const float* __restrict__ h0_ws,
    const float* __restrict__ W_gcn, const float* __restrict__ W_out,
    const float* __restrict__ b_out, float* __restrict__ out2) {
    const int b = blockIdx.x / (HM_C / ICHUNK);
    const int i0 = (blockIdx.x % (HM_C / ICHUNK)) * ICHUNK;
    const int tid = threadIdx.x;           // = d

    __shared__ float arow[ICHUNK * HM_C];  // 2744 B
    __shared__ float tmp_s[ICHUNK * DDIM]; // 3584 B
    __shared__ float h1_s[ICHUNK * DDIM];  // 3584 B

    for (int k = tid; k < ICHUNK * HM_C; k += DDIM)
        arow[k] = A[(i0 + k / HM_C) * HM_C + (k % HM_C)];
    __syncthreads();

    {
        float acc[ICHUNK];
        #pragma unroll
        for (int i = 0; i < ICHUNK; ++i) acc[i] = 0.f;
        for (int j = 0; j < HM_C; ++j) {
            const float v = h0_ws[((size_t)b * HM_C + j) * DDIM + tid];
            #pragma unroll
            for (int i = 0; i < ICHUNK; ++i)
                acc[i] = fmaf(arow[i * HM_C + j], v, acc[i]);
        }
        #pragma unroll
        for (int i = 0; i < ICHUNK; ++i) tmp_s[i * DDIM + tid] = acc[i];
    }
    __syncthreads();

    {
        float acc[ICHUNK];
        #pragma unroll
        for (int i = 0; i < ICHUNK; ++i) acc[i] = 0.f;
        for (int k = 0; k < DDIM; ++k) {
            const float w = W_gcn[k * DDIM + tid];
            #pragma unroll
            for (int i = 0; i < ICHUNK; ++i)
                acc[i] = fmaf(tmp_s[i * DDIM + k], w, acc[i]);
        }
        #pragma unroll
        for (int i = 0; i < ICHUNK; ++i) h1_s[i * DDIM + tid] = fmaxf(acc[i], 0.f);
    }
    __syncthreads();

    if (tid < ICHUNK * 2) {
        const int i = tid >> 1;
        const int o = tid & 1;
        float acc = b_out[o];
        for (int dd = 0; dd < DDIM; ++dd)
            acc = fmaf(h1_s[i * DDIM + dd], W_out[dd * 2 + o], acc);
        out2[((size_t)b * HM_C + i0 + i) * 2 + o] = acc;
    }
}

extern "C" void kernel_launch(void* const* d_in, const int* in_sizes, int n_in,
                              void* d_out, int out_size, void* d_ws, size_t ws_size,
                              hipStream_t stream) {
    const float* hm      = (const float*)d_in[0];
    const float* feat    = (const float*)d_in[1];
    const float* W_embed = (const float*)d_in[2];
    const float* b_embed = (const float*)d_in[3];
    const float* A       = (const float*)d_in[4];
    const float* W_gcn   = (const float*)d_in[5];
    const float* W_out   = (const float*)d_in[6];
    const float* b_out   = (const float*)d_in[7];

    float* out_hm = (float*)d_out;                 // [B,C,H,W] passthrough
    float* out2   = (float*)d_out + HM_ELEMS;      // [B,C,2]

    char* ws = (char*)d_ws;
    float* pconf = (float*)ws;  ws += BC * NWAVE * sizeof(float);  // 50 KB
    int*   pidx  = (int*)ws;    ws += BC * NWAVE * sizeof(int);    // 50 KB
    float* h0_ws = (float*)ws;  // BC*128*4 = 1.606 MB; total ~1.7 MB

    k1_copy_argmax<<<BC, NTHR, 0, stream>>>(hm, out_hm, pconf, pidx);
    k2_embed<<<BC / LCHUNK, NTHR, 0, stream>>>(feat, pconf, pidx,
                                               W_embed, b_embed, h0_ws);
    k3_gcn<<<HM_B * (HM_C / ICHUNK), DDIM, 0, stream>>>(A, h0_ws, W_gcn,
                                                        W_out, b_out, out2);
}